// Round 6
// baseline (24.987 us; speedup 1.0000x reference)
//
#include <hip/hip_runtime.h>
#include <math.h>

#define BB 32
#define TT 200
#define NCC 10
#define FF 2048
#define KK 3
#define NWRITE (2 * NCC * BB * 2)   // 1280 writer blocks: (side, nc, b, f-half)

#define SENT(w) (0x9E3779B9u * (unsigned)((w) + 1))

// Butterfly argmax across a 64-lane wave: max value, ties -> lower index.
// Matches jax.lax.top_k (descending, stable) — verified passing R1/R2/R4/R5.
__device__ inline void wave_argmax(float& v, int& i) {
    #pragma unroll
    for (int m = 1; m < 64; m <<= 1) {
        float ov = __shfl_xor(v, m);
        int   oi = __shfl_xor(i, m);
        if (ov > v || (ov == v && oi < i)) { v = ov; i = oi; }
    }
}

__device__ inline float wave_sum(float v) {
    #pragma unroll
    for (int m = 1; m < 64; m <<= 1) v += __shfl_xor(v, m);
    return v;
}

// ---------------------------------------------------------------------------
// Single kernel. Block 0 = spinner/composer; blocks 1..NWRITE = writers.
// Writer w = bid-1: ((side*NCC + nc)*BB + b)*2 + fc. Wave 0 computes masked
// top-3 (broadcast via LDS) + the BCE term (nc==0,fc==0); all 256 threads
// gather one float4 from each of 3 selected half-rows; LDS-reduce; tid0
// stores partial[w] then RELEASE-stores flags[w]=SENT(w).
// Spinner: acquire-spin on all 1280 flags, reset them, compose the two output
// scalars in wave 0 (fixed-order, deterministic), write d_out.
// ---------------------------------------------------------------------------
__global__ __launch_bounds__(256) void mono_kernel(
        const float* __restrict__ abnr_magn,
        const float* __restrict__ norm_magn,
        const float* __restrict__ abnr_feats,
        const float* __restrict__ norm_feats,
        const float* __restrict__ abnr_sls,
        const float* __restrict__ norm_sls,
        const float* __restrict__ abnr_u,
        const float* __restrict__ norm_u,
        float*    __restrict__ partial /* [NWRITE] */,
        float*    __restrict__ bce     /* [2*BB]   */,
        unsigned* __restrict__ flags   /* [NWRITE] */,
        float*    __restrict__ out) {
    const int bid = blockIdx.x;
    const int tid = threadIdx.x;
    const int lane = tid & 63;
    const int wav  = tid >> 6;

    if (bid == 0) {
        // ---------------- spinner / composer ----------------
        #pragma unroll
        for (int k = 0; k < NWRITE / 256; ++k) {
            const int w = tid + k * 256;
            const unsigned sent = SENT(w);
            while (__hip_atomic_load(&flags[w], __ATOMIC_ACQUIRE,
                                     __HIP_MEMORY_SCOPE_AGENT) != sent)
                __builtin_amdgcn_s_sleep(2);
            flags[w] = 0u;   // reset for the next replay (plain store is fine)
        }
        __syncthreads();     // all flags acquired -> partial/bce visible block-wide

        if (wav == 0) {
            const float third = 1.0f / 3.0f;
            float s = 0.0f;
            #pragma unroll
            for (int k = 0; k < (NCC * BB) / 64; ++k) {
                int i = lane + 64 * k;                    // row in [0, 320)
                float2 pa2 = *(const float2*)(partial + 2 * i);
                float2 pn2 = *(const float2*)(partial + 2 * (NCC * BB + i));
                float l2a = sqrtf(pa2.x + pa2.y) * third; // ||mean over K||
                float l2n = sqrtf(pn2.x + pn2.y) * third;
                float t = fabsf(100.0f - l2a) + l2n;
                s += t * t;
            }
            s = wave_sum(s);

            float s2 = bce[lane];                         // 64 terms, 1 per lane
            s2 = wave_sum(s2);

            if (lane == 0) {
                out[0] = 1e-4f * (s * (1.0f / (float)(NCC * BB)));
                out[1] = -s2 * (1.0f / (float)BB);
            }
        }
        return;
    }

    // ---------------- writer ----------------
    const int w    = bid - 1;
    const int fc   = w & 1;
    const int r    = w >> 1;           // (side*NCC + nc)*BB + b
    const int b    = r % BB;
    const int sn   = r / BB;
    const int side = sn / NCC;
    const int nc   = sn % NCC;

    const float* feats = side ? norm_feats : abnr_feats;

    __shared__ int   s_idx[KK];
    __shared__ float s_red[4];

    // ---- masked top-3 on wave 0 (registers + butterfly argmax) ----
    if (wav == 0) {
        const float* magn = side ? norm_magn : abnr_magn;
        const float* u    = side ? norm_u    : abnr_u;
        const float scale = 1.0f / (1.0f - 0.7f);
        float vv[4];
        int   tv[4];
        if (lane < TT / 4) {
            float4 mg = *(const float4*)(magn + b * TT + lane * 4);
            float4 uu = *(const float4*)(u    + b * TT + lane * 4);
            vv[0] = mg.x * ((uu.x >= 0.7f) ? scale : 0.0f);
            vv[1] = mg.y * ((uu.y >= 0.7f) ? scale : 0.0f);
            vv[2] = mg.z * ((uu.z >= 0.7f) ? scale : 0.0f);
            vv[3] = mg.w * ((uu.w >= 0.7f) ? scale : 0.0f);
            #pragma unroll
            for (int j = 0; j < 4; ++j) tv[j] = lane * 4 + j;
        } else {
            #pragma unroll
            for (int j = 0; j < 4; ++j) { vv[j] = -INFINITY; tv[j] = 1 << 30; }
        }
        int id[KK];
        #pragma unroll
        for (int k = 0; k < KK; ++k) {
            float bv = -INFINITY;
            int   bi = 1 << 30;
            #pragma unroll
            for (int j = 0; j < 4; ++j)
                if (vv[j] > bv || (vv[j] == bv && tv[j] < bi)) { bv = vv[j]; bi = tv[j]; }
            wave_argmax(bv, bi);
            id[k] = bi;
            #pragma unroll
            for (int j = 0; j < 4; ++j)
                if (tv[j] == bi) vv[j] = -INFINITY;
        }
        if (lane < KK) s_idx[lane] = id[lane];

        // BCE term, once per (side, b) — by tid 0 (program-ordered before flag).
        if (nc == 0 && fc == 0 && lane == 0) {
            const float* sls = side ? norm_sls : abnr_sls;
            float v = (sls[b * TT + id[0]] + sls[b * TT + id[1]] +
                       sls[b * TT + id[2]]) * (1.0f / 3.0f);
            bce[side * BB + b] = side ? fmaxf(logf(1.0f - v), -100.0f)
                                      : fmaxf(logf(v), -100.0f);
        }
    }
    __syncthreads();
    const int id0 = s_idx[0], id1 = s_idx[1], id2 = s_idx[2];

    // ---- gather: one float4 per thread from each of 3 half-rows ----
    const size_t base = (size_t)(nc * BB + b) * (TT * FF) + (size_t)fc * (FF / 2) + tid * 4;
    float4 x0 = *(const float4*)(feats + base + (size_t)id0 * FF);
    float4 x1 = *(const float4*)(feats + base + (size_t)id1 * FF);
    float4 x2 = *(const float4*)(feats + base + (size_t)id2 * FF);
    float m, acc = 0.0f;
    m = x0.x + x1.x + x2.x; acc += m * m;
    m = x0.y + x1.y + x2.y; acc += m * m;
    m = x0.z + x1.z + x2.z; acc += m * m;
    m = x0.w + x1.w + x2.w; acc += m * m;

    acc = wave_sum(acc);
    if (lane == 0) s_red[wav] = acc;
    __syncthreads();
    if (tid == 0) {
        partial[w] = s_red[0] + s_red[1] + s_red[2] + s_red[3];
        __hip_atomic_store(&flags[w], SENT(w), __ATOMIC_RELEASE,
                           __HIP_MEMORY_SCOPE_AGENT);
    }
}

extern "C" void kernel_launch(void* const* d_in, const int* in_sizes, int n_in,
                              void* d_out, int out_size, void* d_ws, size_t ws_size,
                              hipStream_t stream) {
    const float* abnr_magn  = (const float*)d_in[0];
    const float* norm_magn  = (const float*)d_in[1];
    const float* abnr_feats = (const float*)d_in[2];
    const float* norm_feats = (const float*)d_in[3];
    const float* abnr_sls   = (const float*)d_in[4];
    const float* norm_sls   = (const float*)d_in[5];
    const float* abnr_u     = (const float*)d_in[6];
    const float* norm_u     = (const float*)d_in[7];
    float* out = (float*)d_out;

    float*    bce     = (float*)d_ws;                       // 64 floats
    float*    partial = (float*)((char*)d_ws + 4096);       // 1280 floats
    unsigned* flags   = (unsigned*)((char*)d_ws + 32768);   // 1280 u32

    mono_kernel<<<NWRITE + 1, 256, 0, stream>>>(abnr_magn, norm_magn,
                                                abnr_feats, norm_feats,
                                                abnr_sls, norm_sls,
                                                abnr_u, norm_u,
                                                partial, bce, flags, out);
}

// Round 7
// 10.124 us; speedup vs baseline: 2.4680x; 2.4680x over previous
//
#include <hip/hip_runtime.h>
#include <math.h>

#define BB 32
#define TT 200
#define NCC 10
#define FF 2048
#define KK 3
#define NWRITE (2 * NCC * BB * 2)   // 1280 writer blocks: (side, nc, b, f-half)

typedef unsigned long long u64;

#define SENT(w)  (0x9E3779B9u * (unsigned)((w) + 1))
#define SENTB(i) (0x85EBCA6Bu * (unsigned)((i) + 7))

__device__ inline u64 pack_slot(unsigned tag, float v) {
    return ((u64)tag << 32) | (u64)__float_as_uint(v);
}

// Butterfly argmax across a 64-lane wave: max value, ties -> lower index.
// Matches jax.lax.top_k (descending, stable) — verified passing R1/R2/R4/R5/R6.
__device__ inline void wave_argmax(float& v, int& i) {
    #pragma unroll
    for (int m = 1; m < 64; m <<= 1) {
        float ov = __shfl_xor(v, m);
        int   oi = __shfl_xor(i, m);
        if (ov > v || (ov == v && oi < i)) { v = ov; i = oi; }
    }
}

__device__ inline float wave_sum(float v) {
    #pragma unroll
    for (int m = 1; m < 64; m <<= 1) v += __shfl_xor(v, m);
    return v;
}

// ---------------------------------------------------------------------------
// Single kernel, single node. Blocks 0..1279 = writers (R4's verified body);
// block 1280 = composer. All cross-block communication is 64-bit RELAXED
// agent-scope atomics packing {sentinel | float} — no acquire/release, hence
// no buffer_inv / buffer_wbl2 cache maintenance (the R6 regression cause).
// ---------------------------------------------------------------------------
__global__ __launch_bounds__(256) void mono_kernel(
        const float* __restrict__ abnr_magn,
        const float* __restrict__ norm_magn,
        const float* __restrict__ abnr_feats,
        const float* __restrict__ norm_feats,
        const float* __restrict__ abnr_sls,
        const float* __restrict__ norm_sls,
        const float* __restrict__ abnr_u,
        const float* __restrict__ norm_u,
        u64* __restrict__ slot  /* [NWRITE] */,
        u64* __restrict__ bslot /* [2*BB]   */,
        float* __restrict__ out) {
    const int bid  = blockIdx.x;
    const int tid  = threadIdx.x;
    const int lane = tid & 63;
    const int wav  = tid >> 6;

    __shared__ float sval[NWRITE];   // composer: decoded partials
    __shared__ float sbce[2 * BB];   // composer: decoded BCE terms
    __shared__ int   s_idx[KK];      // writer: top-3 broadcast
    __shared__ float s_red[4];       // writer: per-wave reduce

    if (bid < NWRITE) {
        // ---------------- writer ----------------
        const int w    = bid;
        const int fc   = w & 1;
        const int r    = w >> 1;           // (side*NCC + nc)*BB + b
        const int b    = r % BB;
        const int sn   = r / BB;
        const int side = sn / NCC;
        const int nc   = sn % NCC;

        const float* feats = side ? norm_feats : abnr_feats;

        // ---- masked top-3 on wave 0 (registers + butterfly argmax) ----
        if (wav == 0) {
            const float* magn = side ? norm_magn : abnr_magn;
            const float* u    = side ? norm_u    : abnr_u;
            const float scale = 1.0f / (1.0f - 0.7f);
            float vv[4];
            int   tv[4];
            if (lane < TT / 4) {
                float4 mg = *(const float4*)(magn + b * TT + lane * 4);
                float4 uu = *(const float4*)(u    + b * TT + lane * 4);
                vv[0] = mg.x * ((uu.x >= 0.7f) ? scale : 0.0f);
                vv[1] = mg.y * ((uu.y >= 0.7f) ? scale : 0.0f);
                vv[2] = mg.z * ((uu.z >= 0.7f) ? scale : 0.0f);
                vv[3] = mg.w * ((uu.w >= 0.7f) ? scale : 0.0f);
                #pragma unroll
                for (int j = 0; j < 4; ++j) tv[j] = lane * 4 + j;
            } else {
                #pragma unroll
                for (int j = 0; j < 4; ++j) { vv[j] = -INFINITY; tv[j] = 1 << 30; }
            }
            int id[KK];
            #pragma unroll
            for (int k = 0; k < KK; ++k) {
                float bv = -INFINITY;
                int   bi = 1 << 30;
                #pragma unroll
                for (int j = 0; j < 4; ++j)
                    if (vv[j] > bv || (vv[j] == bv && tv[j] < bi)) { bv = vv[j]; bi = tv[j]; }
                wave_argmax(bv, bi);
                id[k] = bi;
                #pragma unroll
                for (int j = 0; j < 4; ++j)
                    if (tv[j] == bi) vv[j] = -INFINITY;
            }
            if (lane < KK) s_idx[lane] = id[lane];

            // BCE term, once per (side, b): publish packed {sentinel|float}.
            if (nc == 0 && fc == 0 && lane == 0) {
                const float* sls = side ? norm_sls : abnr_sls;
                float v = (sls[b * TT + id[0]] + sls[b * TT + id[1]] +
                           sls[b * TT + id[2]]) * (1.0f / 3.0f);
                float term = side ? fmaxf(logf(1.0f - v), -100.0f)
                                  : fmaxf(logf(v), -100.0f);
                __hip_atomic_store(&bslot[side * BB + b],
                                   pack_slot(SENTB(side * BB + b), term),
                                   __ATOMIC_RELAXED, __HIP_MEMORY_SCOPE_AGENT);
            }
        }
        __syncthreads();
        const int id0 = s_idx[0], id1 = s_idx[1], id2 = s_idx[2];

        // ---- gather: one float4 per thread from each of 3 half-rows ----
        const size_t base = (size_t)(nc * BB + b) * (TT * FF) +
                            (size_t)fc * (FF / 2) + tid * 4;
        float4 x0 = *(const float4*)(feats + base + (size_t)id0 * FF);
        float4 x1 = *(const float4*)(feats + base + (size_t)id1 * FF);
        float4 x2 = *(const float4*)(feats + base + (size_t)id2 * FF);
        float m, acc = 0.0f;
        m = x0.x + x1.x + x2.x; acc += m * m;
        m = x0.y + x1.y + x2.y; acc += m * m;
        m = x0.z + x1.z + x2.z; acc += m * m;
        m = x0.w + x1.w + x2.w; acc += m * m;

        acc = wave_sum(acc);
        if (lane == 0) s_red[wav] = acc;
        __syncthreads();
        if (tid == 0) {
            float tot = s_red[0] + s_red[1] + s_red[2] + s_red[3];  // >= 0 always
            __hip_atomic_store(&slot[w], pack_slot(SENT(w), tot),
                               __ATOMIC_RELAXED, __HIP_MEMORY_SCOPE_AGENT);
        }
        return;
    }

    // ---------------- composer (block NWRITE, dispatched last) ----------------
    #pragma unroll
    for (int k = 0; k < NWRITE / 256; ++k) {
        const int w = tid + 256 * k;
        const unsigned tag = SENT(w);
        u64 p;
        for (;;) {
            p = __hip_atomic_load(&slot[w], __ATOMIC_RELAXED,
                                  __HIP_MEMORY_SCOPE_AGENT);
            if ((unsigned)(p >> 32) == tag) break;
            __builtin_amdgcn_s_sleep(1);
        }
        sval[w] = __uint_as_float((unsigned)p);
    }
    if (tid < 2 * BB) {
        const unsigned tag = SENTB(tid);
        u64 p;
        for (;;) {
            p = __hip_atomic_load(&bslot[tid], __ATOMIC_RELAXED,
                                  __HIP_MEMORY_SCOPE_AGENT);
            if ((unsigned)(p >> 32) == tag) break;
            __builtin_amdgcn_s_sleep(1);
        }
        sbce[tid] = __uint_as_float((unsigned)p);
    }
    __syncthreads();

    if (wav == 0) {
        const float third = 1.0f / 3.0f;
        float s = 0.0f;
        #pragma unroll
        for (int k = 0; k < (NCC * BB) / 64; ++k) {
            int i = lane + 64 * k;                        // row in [0, 320)
            float pa = sval[2 * i] + sval[2 * i + 1];
            float pn = sval[2 * (NCC * BB + i)] + sval[2 * (NCC * BB + i) + 1];
            float l2a = sqrtf(pa) * third;                // ||mean over K||
            float l2n = sqrtf(pn) * third;
            float t = fabsf(100.0f - l2a) + l2n;
            s += t * t;
        }
        s = wave_sum(s);

        float s2 = sbce[lane];                            // 64 terms, 1/lane
        s2 = wave_sum(s2);

        if (lane == 0) {
            out[0] = 1e-4f * (s * (1.0f / (float)(NCC * BB)));
            out[1] = -s2 * (1.0f / (float)BB);
        }
    }
}

extern "C" void kernel_launch(void* const* d_in, const int* in_sizes, int n_in,
                              void* d_out, int out_size, void* d_ws, size_t ws_size,
                              hipStream_t stream) {
    const float* abnr_magn  = (const float*)d_in[0];
    const float* norm_magn  = (const float*)d_in[1];
    const float* abnr_feats = (const float*)d_in[2];
    const float* norm_feats = (const float*)d_in[3];
    const float* abnr_sls   = (const float*)d_in[4];
    const float* norm_sls   = (const float*)d_in[5];
    const float* abnr_u     = (const float*)d_in[6];
    const float* norm_u     = (const float*)d_in[7];
    float* out = (float*)d_out;

    u64* slot  = (u64*)d_ws;                         // 1280 x 8 B
    u64* bslot = (u64*)((char*)d_ws + 16384);        // 64 x 8 B

    mono_kernel<<<NWRITE + 1, 256, 0, stream>>>(abnr_magn, norm_magn,
                                                abnr_feats, norm_feats,
                                                abnr_sls, norm_sls,
                                                abnr_u, norm_u,
                                                slot, bslot, out);
}